// Round 1
// 3998.400 us; speedup vs baseline: 1.7496x; 1.7496x over previous
//
#include <hip/hip_runtime.h>
#include <math.h>

#define BB 2
#define TT 1024
#define VV 32000
#define HH 2048
#define HK 16
#define HV 32
#define DK 128
#define DV 128
#define QKD 2048
#define VD 4096
#define CONVD 8192
#define QKVZ 12288
#define MM (BB*TT)          // 2048
#define FEPS 1e-6f
#define CH 16

typedef unsigned short u16;
typedef unsigned int   u32;
using bf16x8 = __attribute__((ext_vector_type(8))) short;   // 8 bf16 (4 VGPRs)
using f32x4  = __attribute__((ext_vector_type(4))) float;   // MFMA accumulator

__device__ __forceinline__ float wave64_sum(float x) {
#pragma unroll
  for (int off = 32; off > 0; off >>= 1) x += __shfl_xor(x, off, 64);
  return x;
}

// fp32 -> bf16 hi (RNE) + bf16 lo (RNE of exact residual). hi+lo ~17 mantissa bits.
__device__ __forceinline__ void bsplit(float x, u16& h, u16& l) {
  u32 u  = __float_as_uint(x);
  u32 hb = (u + 0x7FFFu + ((u >> 16) & 1u)) & 0xFFFF0000u;
  h = (u16)(hb >> 16);
  float lf = x - __uint_as_float(hb);          // exact in fp32
  u32 u2 = __float_as_uint(lf);
  l = (u16)((u2 + 0x7FFFu + ((u2 >> 16) & 1u)) >> 16);
}

// ---------------------------------------------------------------- A-plane split
// Ah/Al[M][K] bf16 <- (optionally gathered) fp32 src. grid: (M, K/1024) x 256
__global__ __launch_bounds__(256) void split_a(
    const float* __restrict__ src, const int* __restrict__ ids,
    u16* __restrict__ Ah, u16* __restrict__ Al, int K) {
  const int row = blockIdx.x;
  const int col = blockIdx.y * 1024 + threadIdx.x * 4;
  const int srow = ids ? ids[row] : row;
  float4 x = *(const float4*)(src + (size_t)srow * K + col);
  u16 h0, h1, h2, h3, l0, l1, l2, l3;
  bsplit(x.x, h0, l0); bsplit(x.y, h1, l1);
  bsplit(x.z, h2, l2); bsplit(x.w, h3, l3);
  ushort4 hv = {h0, h1, h2, h3}, lv = {l0, l1, l2, l3};
  *(ushort4*)(Ah + (size_t)row * K + col) = hv;
  *(ushort4*)(Al + (size_t)row * K + col) = lv;
}

// ---------------------------------------------------------------- B transpose+split
// W fp32 [K][Nfull], cols [n0, n0+NC) -> Bh/Bl bf16 [NC][K] (B^T planes, k-contig).
// grid: (NC/64, K/64) x 256
__global__ __launch_bounds__(256) void transpose_split(
    const float* __restrict__ W, int Nfull, int K, int n0,
    u16* __restrict__ Bh, u16* __restrict__ Bl) {
  __shared__ float ts[64][65];                 // +1 pad: conflict-free column reads
  const int nb = blockIdx.x * 64, kb = blockIdx.y * 64;
  const int c = threadIdx.x & 63, r4 = threadIdx.x >> 6;
#pragma unroll
  for (int i = 0; i < 16; i++) {
    const int r = i * 4 + r4;
    ts[r][c] = W[(size_t)(kb + r) * Nfull + n0 + nb + c];
  }
  __syncthreads();
#pragma unroll
  for (int i = 0; i < 16; i++) {
    const int r = i * 4 + r4;                  // local output row (n)
    float v = ts[c][r];                        // = W[kb+c][n0+nb+r]
    u16 h, l; bsplit(v, h, l);
    Bh[(size_t)(nb + r) * K + kb + c] = h;
    Bl[(size_t)(nb + r) * K + kb + c] = l;
  }
}

// ---------------------------------------------------------------- bf16x4 split MFMA GEMM
// C[128x128 tile] += (Ah+Al)(Bh+Bl) via 4 mfma products, fp32 accum.
// A planes [M][K], B^T planes [N][K] (both k-contiguous bf16). BK=32, 4 waves,
// wave tile 64x64 (4x4 fragments of 16x16x32). LDS rows padded to 40 u16 (80 B)
// so 16-lane x 16-row fragment reads are 2-way/bank (free, G4).
#define LDT 40
__global__ __launch_bounds__(256) void gemm_mfma3(
    const u16* __restrict__ Ah, const u16* __restrict__ Al,
    const u16* __restrict__ Bh, const u16* __restrict__ Bl,
    float* __restrict__ C, int ldc, int K, int bn0) {
  __shared__ __align__(16) u16 sAh[128 * LDT], sAl[128 * LDT];
  __shared__ __align__(16) u16 sBh[128 * LDT], sBl[128 * LDT];
  const int tid  = threadIdx.x;
  const int lane = tid & 63, wave = tid >> 6;
  const int bm = blockIdx.y * 128, bn = blockIdx.x * 128;
  const int wm = (wave & 1) * 64, wn = (wave >> 1) * 64;
  // staging: thread -> (row = tid>>2, 16B-chunk q = tid&3), plus row+64
  const int r0 = tid >> 2, q0 = tid & 3;
  const size_t ro2 = (size_t)64 * K;
  const u16* gA_h = Ah + (size_t)(bm + r0) * K + q0 * 8;
  const u16* gA_l = Al + (size_t)(bm + r0) * K + q0 * 8;
  const u16* gB_h = Bh + (size_t)(bn + r0) * K + q0 * 8;
  const u16* gB_l = Bl + (size_t)(bn + r0) * K + q0 * 8;
  u16* wA_h = &sAh[r0 * LDT + q0 * 8];
  u16* wA_l = &sAl[r0 * LDT + q0 * 8];
  u16* wB_h = &sBh[r0 * LDT + q0 * 8];
  u16* wB_l = &sBl[r0 * LDT + q0 * 8];
  const int fr = lane & 15, fq = (lane >> 4) * 8;   // fragment row / k-offset

  f32x4 acc[4][4];
#pragma unroll
  for (int m = 0; m < 4; m++)
#pragma unroll
    for (int n = 0; n < 4; n++) acc[m][n] = (f32x4){0.f, 0.f, 0.f, 0.f};

  for (int k0 = 0; k0 < K; k0 += 32) {
    uint4 va0 = *(const uint4*)(gA_h + k0);
    uint4 va1 = *(const uint4*)(gA_h + k0 + ro2);
    uint4 va2 = *(const uint4*)(gA_l + k0);
    uint4 va3 = *(const uint4*)(gA_l + k0 + ro2);
    uint4 vb0 = *(const uint4*)(gB_h + k0);
    uint4 vb1 = *(const uint4*)(gB_h + k0 + ro2);
    uint4 vb2 = *(const uint4*)(gB_l + k0);
    uint4 vb3 = *(const uint4*)(gB_l + k0 + ro2);
    __syncthreads();
    *(uint4*)wA_h = va0; *(uint4*)(wA_h + 64 * LDT) = va1;
    *(uint4*)wA_l = va2; *(uint4*)(wA_l + 64 * LDT) = va3;
    *(uint4*)wB_h = vb0; *(uint4*)(wB_h + 64 * LDT) = vb1;
    *(uint4*)wB_l = vb2; *(uint4*)(wB_l + 64 * LDT) = vb3;
    __syncthreads();
    bf16x8 fah[4], fal[4], fbh[4], fbl[4];
#pragma unroll
    for (int m = 0; m < 4; m++) {
      fah[m] = *(const bf16x8*)&sAh[(wm + m * 16 + fr) * LDT + fq];
      fal[m] = *(const bf16x8*)&sAl[(wm + m * 16 + fr) * LDT + fq];
    }
#pragma unroll
    for (int n = 0; n < 4; n++) {
      fbh[n] = *(const bf16x8*)&sBh[(wn + n * 16 + fr) * LDT + fq];
      fbl[n] = *(const bf16x8*)&sBl[(wn + n * 16 + fr) * LDT + fq];
    }
#pragma unroll
    for (int m = 0; m < 4; m++)
#pragma unroll
      for (int n = 0; n < 4; n++) {
        acc[m][n] = __builtin_amdgcn_mfma_f32_16x16x32_bf16(fah[m], fbh[n], acc[m][n], 0, 0, 0);
        acc[m][n] = __builtin_amdgcn_mfma_f32_16x16x32_bf16(fah[m], fbl[n], acc[m][n], 0, 0, 0);
        acc[m][n] = __builtin_amdgcn_mfma_f32_16x16x32_bf16(fal[m], fbh[n], acc[m][n], 0, 0, 0);
        acc[m][n] = __builtin_amdgcn_mfma_f32_16x16x32_bf16(fal[m], fbl[n], acc[m][n], 0, 0, 0);
      }
  }
  // C/D layout (verified m89): col = lane&15, row = (lane>>4)*4 + reg
  const int crow = (lane >> 4) * 4, ccol = lane & 15;
#pragma unroll
  for (int m = 0; m < 4; m++) {
    const int row = bm + wm + m * 16 + crow;
#pragma unroll
    for (int n = 0; n < 4; n++) {
      float* Cp = C + (size_t)row * ldc + bn0 + bn + wn + n * 16 + ccol;
#pragma unroll
      for (int r = 0; r < 4; r++) Cp[(size_t)r * ldc] = acc[m][n][r];
    }
  }
}

// ---------------------------------------------------------------- ba = x @ W_ba  (N=64)
__global__ __launch_bounds__(64) void ba_gemm(
    const int* __restrict__ ids, const float* __restrict__ emb,
    const float* __restrict__ Wba, float* __restrict__ ba) {
  __shared__ __align__(16) float xs[HH];
  const int r = blockIdx.x, tid = threadIdx.x;
  const float* xr = emb + (size_t)ids[r] * HH;
  for (int i = tid * 4; i < HH; i += 64 * 4)
    *(float4*)&xs[i] = *(const float4*)(xr + i);
  __syncthreads();
  float acc = 0.f;
  for (int k = 0; k < HH; k++) acc = fmaf(xs[k], Wba[k * 64 + tid], acc);
  ba[r * 64 + tid] = acc;
}

// ---------------------------------------------------------------- causal depthwise conv(K=4)+SiLU
__global__ __launch_bounds__(256) void conv_kernel(
    const float* __restrict__ qkvz, const float* __restrict__ convw,
    const float* __restrict__ convb, float* __restrict__ qh,
    float* __restrict__ kh, float* __restrict__ vh) {
  const int r = blockIdx.x;               // b*T + t
  const int b = r >> 10, t = r & 1023;
  const int c = blockIdx.y * 256 + threadIdx.x;
  float4 w = *(const float4*)(convw + c * 4);
  const float* col = qkvz + (size_t)r * QKVZ + c;
  float acc = convb[c];
  if (t >= 3) {
    acc = fmaf(col[-3 * QKVZ], w.x, acc);
    acc = fmaf(col[-2 * QKVZ], w.y, acc);
    acc = fmaf(col[-1 * QKVZ], w.z, acc);
    acc = fmaf(col[0],         w.w, acc);
  } else {
    const float wj[4] = {w.x, w.y, w.z, w.w};
#pragma unroll
    for (int j = 0; j < 4; j++) {
      int tt = t - 3 + j;
      if (tt >= 0) acc = fmaf(col[(j - 3) * (int)QKVZ], wj[j], acc);
    }
  }
  float s = acc / (1.f + expf(-acc));     // SiLU
  const int hi = (c >> 7) & 15, d = c & 127;
  if (c < QKD)            qh[((size_t)(b * HK + hi) * TT + t) * DK + d] = s;
  else if (c < 2 * QKD)   kh[((size_t)(b * HK + hi) * TT + t) * DK + d] = s;
  else {
    const int hv = (c - 2 * QKD) >> 7;
    vh[((size_t)(b * HV + hv) * TT + t) * DV + d] = s;
  }
}

// ---------------------------------------------------------------- per-head l2norm of q,k
__global__ __launch_bounds__(64) void l2norm_qk(float* __restrict__ qh, float* __restrict__ kh) {
  const int NQK = BB * HK * TT;           // 32768
  const int id = blockIdx.x;
  const bool isq = id < NQK;
  float* p = (isq ? qh : kh) + (size_t)(isq ? id : id - NQK) * DK;
  const int tid = threadIdx.x;
  float x0 = p[tid], x1 = p[tid + 64];
  float ss = wave64_sum(x0 * x0 + x1 * x1);
  float r = rsqrtf(ss + FEPS);
  if (isq) r *= 0.08838834764831845f;     // DK^-0.5
  p[tid] = x0 * r;
  p[tid + 64] = x1 * r;
}

// ---------------------------------------------------------------- beta, g from ba
__global__ __launch_bounds__(256) void bg_kernel(
    const float* __restrict__ ba, const float* __restrict__ A_log,
    const float* __restrict__ dt_bias, float* __restrict__ g,
    float* __restrict__ beta) {
  const int idx = blockIdx.x * 256 + threadIdx.x;  // (b*HV + h)*T + t
  const int t = idx & (TT - 1);
  const int h = (idx >> 10) & (HV - 1);
  const int b = idx >> 15;
  const float* bar = ba + (size_t)(b * TT + t) * 64;
  beta[idx] = 1.f / (1.f + expf(-bar[h]));
  float x = bar[32 + h] + dt_bias[h];
  float sp = (x > 20.f) ? x : log1pf(expf(x));
  g[idx] = -expf(A_log[h]) * sp;
}

// ---------------------------------------------------------------- gated delta-rule scan
__global__ __launch_bounds__(256) void scan_kernel(
    const float* __restrict__ qh, const float* __restrict__ kh,
    const float* __restrict__ vh, const float* __restrict__ g,
    const float* __restrict__ beta, float* __restrict__ o) {
  const int bh = blockIdx.x;
  const int b = bh >> 5, h = bh & 31, hkid = h >> 1;
  const float* qp = qh + (size_t)(b * HK + hkid) * TT * DK;
  const float* kp = kh + (size_t)(b * HK + hkid) * TT * DK;
  const float* vp = vh + (size_t)bh * TT * DV;
  const float* gp = g + (size_t)bh * TT;
  const float* bp = beta + (size_t)bh * TT;
  const int tid = threadIdx.x;
  const int v = tid >> 1, half = tid & 1;
  __shared__ __align__(16) float qs[CH * 128], ks[CH * 128], vs[CH * 128], os[CH * 128];
  __shared__ float dsc[CH], bsc[CH];
  float S[64];
#pragma unroll
  for (int i = 0; i < 64; i++) S[i] = 0.f;

  for (int t0 = 0; t0 < TT; t0 += CH) {
    { // stage chunk
      const int base = tid * 8;
      *(float4*)&qs[base]     = *(const float4*)(qp + t0 * 128 + base);
      *(float4*)&qs[base + 4] = *(const float4*)(qp + t0 * 128 + base + 4);
      *(float4*)&ks[base]     = *(const float4*)(kp + t0 * 128 + base);
      *(float4*)&ks[base + 4] = *(const float4*)(kp + t0 * 128 + base + 4);
      *(float4*)&vs[base]     = *(const float4*)(vp + t0 * 128 + base);
      *(float4*)&vs[base + 4] = *(const float4*)(vp + t0 * 128 + base + 4);
      if (tid < CH) { dsc[tid] = expf(gp[t0 + tid]); bsc[tid] = bp[t0 + tid]; }
    }
    __syncthreads();
    for (int i = 0; i < CH; i++) {
      const float d = dsc[i], bt = bsc[i];
      const float* kk = &ks[i * 128 + half * 64];
      const float* qq = &qs[i * 128 + half * 64];
      float kp0 = 0.f, kp1 = 0.f, kp2 = 0.f, kp3 = 0.f;
#pragma unroll
      for (int j = 0; j < 64; j += 4) {
        float4 k4 = *(const float4*)&kk[j];
        kp0 = fmaf(k4.x, S[j],     kp0);
        kp1 = fmaf(k4.y, S[j + 1], kp1);
        kp2 = fmaf(k4.z, S[j + 2], kp2);
        kp3 = fmaf(k4.w, S[j + 3], kp3);
      }
      float kvp = (kp0 + kp1) + (kp2 + kp3);
      float kv = d * (kvp + __shfl_xor(kvp, 1, 64));
      float delta = (vs[i * 128 + v] - kv) * bt;
      float o0 = 0.f, o1 = 0.f, o2 = 0.f, o3 = 0.f;
#pragma unroll
      for (int j = 0; j < 64; j += 4) {
        float4 k4 = *(const float4*)&kk[j];
        float4 q4 = *(const float4*)&qq[j];
        S[j]     = fmaf(k4.x, delta, S[j]     * d);
        S[j + 1] = fmaf(k4.y, delta, S[j + 1] * d);
        S[j + 2] = fmaf(k4.z, delta, S[j + 2] * d);
        S[j + 3] = fmaf(k4.w, delta, S[j + 3] * d);
        o0 = fmaf(q4.x, S[j],     o0);
        o1 = fmaf(q4.y, S[j + 1], o1);
        o2 = fmaf(q4.z, S[j + 2], o2);
        o3 = fmaf(q4.w, S[j + 3], o3);
      }
      float op_ = (o0 + o1) + (o2 + o3);
      float oo = op_ + __shfl_xor(op_, 1, 64);
      if (!half) os[i * 128 + v] = oo;
    }
    __syncthreads();
    { // write chunk: o[b, t, h, :]
      const int base = tid * 8;
      const int i = base >> 7, dd = base & 127;
      float4 o0 = *(float4*)&os[base];
      float4 o1 = *(float4*)&os[base + 4];
      float* outp = o + ((size_t)(b * TT + t0 + i) * HV + h) * DV + dd;
      *(float4*)outp       = o0;
      *(float4*)(outp + 4) = o1;
    }
    __syncthreads();
  }
}

// ---------------------------------------------------------------- gate with silu(z) + per-head RMSNorm
__global__ __launch_bounds__(64) void gate_norm(
    float* __restrict__ o, const float* __restrict__ qkvz,
    const float* __restrict__ norm_w) {
  const int id = blockIdx.x;              // (b*T+t)*HV + h
  const int row = id >> 5, h = id & 31;
  float* op = o + (size_t)id * DV;
  const float* zp = qkvz + (size_t)row * QKVZ + 2 * QKD + VD + h * DV;
  const int tid = threadIdx.x;
  float x0 = op[tid], x1 = op[tid + 64];
  float z0 = zp[tid], z1 = zp[tid + 64];
  x0 *= z0 / (1.f + expf(-z0));
  x1 *= z1 / (1.f + expf(-z1));
  float ss = wave64_sum(x0 * x0 + x1 * x1);
  float r = rsqrtf(ss * (1.f / 128.f) + FEPS);
  op[tid]      = x0 * r * norm_w[tid];
  op[tid + 64] = x1 * r * norm_w[tid + 64];
}

// ---------------------------------------------------------------- launch
extern "C" void kernel_launch(void* const* d_in, const int* in_sizes, int n_in,
                              void* d_out, int out_size, void* d_ws, size_t ws_size,
                              hipStream_t stream) {
  const int*   ids     = (const int*)d_in[0];
  const float* emb     = (const float*)d_in[1];
  const float* Wqkvz   = (const float*)d_in[2];
  const float* Wba     = (const float*)d_in[3];
  const float* convw   = (const float*)d_in[4];
  const float* convb   = (const float*)d_in[5];
  const float* A_log   = (const float*)d_in[6];
  const float* dt_bias = (const float*)d_in[7];
  const float* norm_w  = (const float*)d_in[8];
  const float* Wout    = (const float*)d_in[9];
  const float* Wlm     = (const float*)d_in[10];
  float* out = (float*)d_out;

  float* p = (float*)d_ws;
  float* qkvz  = p; p += (size_t)MM * QKVZ;        // also LM-head B^T scratch (dead after gate_norm)
  float* ba    = p; p += (size_t)MM * 64;
  float* qh    = p; p += (size_t)BB * HK * TT * DK; // also A_hi plane (dead in GEMM windows)
  float* kh    = p; p += (size_t)BB * HK * TT * DK; // also A_lo plane
  float* vh    = p; p += (size_t)BB * HV * TT * DV;
  float* gbuf  = p; p += (size_t)BB * HV * TT;
  float* betab = p; p += (size_t)BB * HV * TT;
  float* obuf  = p; p += (size_t)MM * VD;
  float* h2    = p; p += (size_t)MM * HH;

  // scratch aliases (all windows verified non-overlapping in time):
  u16* Ah  = (u16*)qh;
  u16* Al  = (u16*)kh;
  u16* Bh_o = (u16*)out;                           // d_out as scratch pre-LM-GEMM
  u16* Bl_o = Bh_o + (size_t)8192 * 2048;
  u16* Bh_q = (u16*)qkvz;                          // qkvz region as LM scratch
  u16* Bl_q = Bh_q + (size_t)8192 * 2048;

  // ---- qkvz = gather(emb, ids) @ W_qkvz   (bf16x4 MFMA, 2 N-chunks)
  split_a<<<dim3(MM, HH / 1024), 256, 0, stream>>>(emb, ids, Ah, Al, HH);
  transpose_split<<<dim3(128, HH / 64), 256, 0, stream>>>(Wqkvz, QKVZ, HH, 0, Bh_o, Bl_o);
  gemm_mfma3<<<dim3(64, MM / 128), 256, 0, stream>>>(Ah, Al, Bh_o, Bl_o, qkvz, QKVZ, HH, 0);
  transpose_split<<<dim3(64, HH / 64), 256, 0, stream>>>(Wqkvz, QKVZ, HH, 8192, Bh_o, Bl_o);
  gemm_mfma3<<<dim3(32, MM / 128), 256, 0, stream>>>(Ah, Al, Bh_o, Bl_o, qkvz, QKVZ, HH, 8192);

  ba_gemm<<<MM, 64, 0, stream>>>(ids, emb, Wba, ba);
  conv_kernel<<<dim3(MM, CONVD / 256), 256, 0, stream>>>(qkvz, convw, convb, qh, kh, vh);
  l2norm_qk<<<2 * BB * HK * TT, 64, 0, stream>>>(qh, kh);
  bg_kernel<<<(BB * HV * TT) / 256, 256, 0, stream>>>(ba, A_log, dt_bias, gbuf, betab);
  scan_kernel<<<BB * HV, 256, 0, stream>>>(qh, kh, vh, gbuf, betab, obuf);
  gate_norm<<<MM * HV, 64, 0, stream>>>(obuf, qkvz, norm_w);

  // ---- h2 = obuf @ W_out   (K = 4096)
  split_a<<<dim3(MM, VD / 1024), 256, 0, stream>>>(obuf, nullptr, Ah, Al, VD);
  transpose_split<<<dim3(HH / 64, VD / 64), 256, 0, stream>>>(Wout, HH, VD, 0, Bh_o, Bl_o);
  gemm_mfma3<<<dim3(HH / 128, MM / 128), 256, 0, stream>>>(Ah, Al, Bh_o, Bl_o, h2, HH, VD, 0);

  // ---- out = h2 @ W_lm   (4 N-chunks, scratch in dead qkvz region)
  split_a<<<dim3(MM, HH / 1024), 256, 0, stream>>>(h2, nullptr, Ah, Al, HH);
  const int n0s[4] = {0, 8192, 16384, 24576};
  const int ncs[4] = {8192, 8192, 8192, 7424};
  for (int i = 0; i < 4; i++) {
    transpose_split<<<dim3(ncs[i] / 64, HH / 64), 256, 0, stream>>>(Wlm, VV, HH, n0s[i], Bh_q, Bl_q);
    gemm_mfma3<<<dim3(ncs[i] / 128, MM / 128), 256, 0, stream>>>(Ah, Al, Bh_q, Bl_q, out, VV, HH, n0s[i]);
  }
}